// Round 7
// baseline (414.914 us; speedup 1.0000x reference)
//
#include <hip/hip_runtime.h>

#define DI __device__ __forceinline__

using floatx4 = __attribute__((ext_vector_type(4))) float;
using bf16x8  = __attribute__((ext_vector_type(8))) short;
using uintx4  = __attribute__((ext_vector_type(4))) unsigned int;

constexpr int T_STEPS = 16384;
constexpr int NN      = 97;
constexpr int M_TOT   = T_STEPS * 6;   // 98304 rows of the (t,h) x channel matrices
constexpr int CHUNK   = 8;             // stored steps per chunk (smaller -> 776 blocks, 3/CU)
constexpr int WARM    = 12;            // warm-up steps (absmax flat 64->24->16->12)
constexpr int NCHUNK  = T_STEPS / CHUNK;   // 2048

// ---------------- ws layout (bytes, all 256B aligned) ----------------
constexpr size_t AL_OFF = 0;                  constexpr size_t AL_SZ = (size_t)M_TOT*128*2; // al: [M][128] bf16 (97 used, zero-pad)
constexpr size_t F1_OFF = AL_OFF + AL_SZ;     constexpr size_t F1_SZ = (size_t)M_TOT*224*2; // f1: [M][224] bf16 (194 used)
constexpr size_t F2_OFF = F1_OFF + F1_SZ;     constexpr size_t F2_SZ = F1_SZ;
constexpr size_t F3_OFF = F2_OFF + F2_SZ;     constexpr size_t F3_SZ = (size_t)M_TOT*112*2; // f3: [M][112] bf16 (97 used)
constexpr size_t W1_OFF = F3_OFF + F3_SZ;     constexpr size_t W1_SZ = (size_t)3*224*128*2;
constexpr size_t W2_OFF = W1_OFF + W1_SZ;     constexpr size_t W2_SZ = (size_t)3*224*224*2;
constexpr size_t W3_OFF = W2_OFF + W2_SZ;     constexpr size_t W3_SZ = (size_t)3*112*224*2;
constexpr size_t B1_OFF = W3_OFF + W3_SZ;
constexpr size_t B2_OFF = B1_OFF + 1024;
constexpr size_t B3_OFF = B2_OFF + 1024;
constexpr size_t ST_OFF = B3_OFF + 1024;      // stats: [0..96]=sum, [128..224]=sumsq
constexpr size_t ZP_OFF = ST_OFF + 1024;      // 256B zero page (OOB redirect for global_load_lds)
// xp (bf16 [T*97][24], 76.3 MB) aliased onto f1+f2 (88.5 MB): dead before conv1 writes f1.
constexpr size_t XP_OFF = F1_OFF;

DI short f2bf(float f){
    union { float f; unsigned u; } a; a.f = f;
    unsigned r = (a.u + 0x7FFFu + ((a.u >> 16) & 1u)) >> 16;
    return (short)r;
}
DI float bf2f(short s){
    union { unsigned u; float f; } a; a.u = ((unsigned)(unsigned short)s) << 16;
    return a.f;
}
DI float fsig(float x){
    float e = __builtin_amdgcn_exp2f(x * -1.442695041f);
    return __builtin_amdgcn_rcpf(1.0f + e);
}
DI float ftanh(float x){
    float e = __builtin_amdgcn_exp2f(x * 2.885390082f);   // exp(2x)
    return 1.0f - 2.0f * __builtin_amdgcn_rcpf(e + 1.0f); // graceful at +-inf
}

// async global->LDS, 16B per lane; LDS dest must be wave-uniform base + lane*16
DI void gload16(const void* g, void* l) {
    __builtin_amdgcn_global_load_lds(
        (const __attribute__((address_space(1))) unsigned int*)g,
        (__attribute__((address_space(3))) unsigned int*)l, 16, 0, 0);
}

// ---------------- weight repack (all three convs in one dispatch) ----------------
// layout: Wg[ks][kh][q][n][j]: k = ks*32 + q*8 + j (zero-padded), value = Wc[n][k][kh][kw=1]
DI void repack_one(const float* Wc, const float* bc, short* wdst, float* bdst,
                   int COUT, int CIN, int NT, int i)
{
    int j  = i & 7;
    int t1 = i >> 3;
    int n  = t1 % NT;
    int t2 = t1 / NT;
    int qq = t2 & 3;
    int t3 = t2 >> 2;
    int kh = t3 % 3;
    int ks = t3 / 3;
    int k  = ks*32 + qq*8 + j;
    float v = 0.f;
    if (n < COUT && k < CIN) v = Wc[((n*CIN + k)*3 + kh)*3 + 1]; // kw=1 only (W=1, pad=1)
    wdst[i] = f2bf(v);
    if (i < NT) bdst[i] = (i < COUT) ? bc[i] : 0.f;
}

constexpr int RT1 = 3*224*128;
constexpr int RT2 = RT1 + 3*224*224;
constexpr int RT3 = RT2 + 3*112*224;

__global__ __launch_bounds__(256) void repack_all(
    const float* __restrict__ Wc1, const float* __restrict__ bc1, short* __restrict__ w1, float* __restrict__ b1,
    const float* __restrict__ Wc2, const float* __restrict__ bc2, short* __restrict__ w2, float* __restrict__ b2,
    const float* __restrict__ Wc3, const float* __restrict__ bc3, short* __restrict__ w3, float* __restrict__ b3)
{
    int idx = blockIdx.x*256 + threadIdx.x;
    if (idx < RT1)       repack_one(Wc1, bc1, w1, b1, 194,  97, 224, idx);
    else if (idx < RT2)  repack_one(Wc2, bc2, w2, b2, 194, 194, 224, idx - RT1);
    else if (idx < RT3)  repack_one(Wc3, bc3, w3, b3,  97, 194, 112, idx - RT2);
}

// ---------------- x-projection: xp[t,n,g] = b_ih[g]+b_hh[g] + sum_f X[t,n,f]*Wih[g,f] ----------------
__global__ __launch_bounds__(256) void xproj_kernel(
    const float* __restrict__ X, const float* __restrict__ Wih,
    const float* __restrict__ bih, const float* __restrict__ bhh,
    short* __restrict__ xp)
{
    const int idx = blockIdx.x*256 + threadIdx.x;   // t*97+n, exactly T*97 threads
    const floatx4* xv = (const floatx4*)(X + (size_t)idx*12);
    floatx4 x0 = xv[0], x1 = xv[1], x2 = xv[2];
    float xr[12];
    #pragma unroll
    for (int f=0; f<4; ++f){ xr[f]=x0[f]; xr[4+f]=x1[f]; xr[8+f]=x2[f]; }

    short o16[24];
    #pragma unroll
    for (int g=0; g<24; ++g) {
        float s = bih[g] + bhh[g];
        #pragma unroll
        for (int f=0; f<12; ++f) s = fmaf(xr[f], Wih[g*12+f], s);
        o16[g] = f2bf(s);
    }
    uintx4* dst = (uintx4*)(xp + (size_t)idx*24);    // 48B per row, 16B aligned
    #pragma unroll
    for (int v=0; v<3; ++v) dst[v] = *(const uintx4*)(&o16[v*8]);
}

// ---------------- LSTM: 97 nodes x 2048 chunks independent, warm-up truncated recurrence ----------------
__global__ __launch_bounds__(256) void lstm_kernel(
    const short* __restrict__ xp, const float* __restrict__ Whh,
    short* __restrict__ al)
{
    const int u  = blockIdx.x*256 + threadIdx.x;   // 0..198655 (776 blocks * 256 exactly)
    const int n  = u % NN;
    const int ch = u / NN;                          // 0..2047
    const int ts = ch*CHUNK;
    const int te = ts + CHUNK;
    int t0 = ts - WARM; if (t0 < 0) t0 = 0;         // ch 0 starts exactly from the true init

    float h[6], c[6];
    #pragma unroll
    for (int j=0;j<6;++j){ h[j]=0.f; c[j]=0.f; }

    for (int t = t0; t < te; ++t) {
        const uintx4* xv = (const uintx4*)(xp + (size_t)(t*NN + n)*24);
        uintx4 p0 = xv[0], p1 = xv[1], p2 = xv[2];
        bf16x8 b0 = __builtin_bit_cast(bf16x8, p0);
        bf16x8 b1 = __builtin_bit_cast(bf16x8, p1);
        bf16x8 b2 = __builtin_bit_cast(bf16x8, p2);
        float xr[24];
        #pragma unroll
        for (int f=0; f<8; ++f){ xr[f]=bf2f(b0[f]); xr[8+f]=bf2f(b1[f]); xr[16+f]=bf2f(b2[f]); }

        float gg[24];
        #pragma unroll
        for (int g=0; g<24; ++g) {
            float s = xr[g];
            #pragma unroll
            for (int j=0; j<6; ++j) s = fmaf(h[j], Whh[g*6+j], s);
            gg[g] = s;
        }
        #pragma unroll
        for (int j=0;j<6;++j){
            float ig = fsig(gg[j]);
            float fg = fsig(gg[6+j]);
            float cg = ftanh(gg[12+j]);
            float og = fsig(gg[18+j]);
            c[j] = fmaf(fg, c[j], ig*cg);
            h[j] = ftanh(og * ftanh(c[j]));          // extra tanh, fed back (matches ref)
        }
        if (t >= ts) {
            int base = (t*6)*128 + n;                // A[m=(t,j)][k=n], stride 128
            #pragma unroll
            for (int j=0;j<6;++j) al[base + j*128] = f2bf(h[j]);
        }
    }
}

// ---------------- pipelined conv as 3-tap (kh) GEMM, bf16 MFMA 16x16x32 ----------------
// Block = 256 thr (4 waves), tile 256 rows x 112 cols (N split via blockIdx.y for NT=224).
// Wave owns 64 rows (mf=4) x 112 cols (nf=7). Double-buffered A+B LDS; stage(ks+1)
// issued before waiting on ks via raw s_waitcnt vmcnt(11) (11 vmem issues per wave
// per k-step, tails duplicated across all 4 waves to keep counts wave-uniform)
// + raw s_barrier. 78.7 KB LDS -> 2 blocks/CU = 8 waves/CU = 2 waves/SIMD.
template<int KP, int NTF, bool STATS>
__global__ __launch_bounds__(256) void conv_pipe(
    const short* __restrict__ In, const short* __restrict__ Wm,
    const float* __restrict__ bias, short* __restrict__ Out,
    float* __restrict__ stats, const short* __restrict__ zp)
{
    constexpr int KS   = KP/32;
    constexpr int ROWS = 258;            // 256 + +-1 halo
    constexpr int ACHR = 4*ROWS;         // 1032 real A chunks (pad to 1088)
    __shared__ alignas(16) short Abuf[2][1088*8];   // 34.8 KB
    __shared__ alignas(16) short Bbuf[2][1344*8];   // 43.0 KB
    __shared__ float sst[2][112];

    const int tid   = threadIdx.x;
    const int lane  = tid & 63;
    const int wv    = tid >> 6;
    const int l16   = lane & 15;
    const int q     = lane >> 4;
    const int m0    = blockIdx.x * 256;
    const int nbase = blockIdx.y * 112;

    if (STATS && tid < 112){ sst[0][tid]=0.f; sst[1][tid]=0.f; }

    auto stageA = [&](int ks, int b) {
        const int k0 = ks*32;
        #pragma unroll
        for (int it=0; it<4; ++it) {                 // chunks 0..1023 (all real)
            int c  = it*256 + tid;
            int cq = c / ROWS;
            int cr = c - cq*ROWS;
            int mg = m0 - 1 + cr;
            const short* src = (mg >= 0 && mg < M_TOT) ? In + (size_t)mg*KP + k0 + cq*8 : zp;
            gload16(src, &Abuf[b][c*8]);
        }
        {                                            // tail 1024..1087, all 4 waves (dup ok)
            int c  = 1024 + (tid & 63);
            const short* src = zp;
            if (c < ACHR) {                          // real only for c < 1032 (cq==3)
                int cr = c - 3*ROWS;
                int mg = m0 - 1 + cr;
                if (mg >= 0 && mg < M_TOT) src = In + (size_t)mg*KP + k0 + 3*8;
            }
            gload16(src, &Abuf[b][c*8]);
        }
    };
    auto stageB = [&](int ks, int b) {
        #pragma unroll
        for (int it=0; it<5; ++it) {                 // chunks 0..1279
            int c    = it*256 + tid;
            int run  = c / 112;
            int ridx = c - run*112;
            const short* src = Wm + ((size_t)(ks*12 + run)*NTF + nbase + ridx)*8;
            gload16(src, &Bbuf[b][c*8]);
        }
        {                                            // tail 1280..1343, all 4 waves (dup ok)
            int c    = 1280 + (tid & 63);
            int run  = c / 112;
            int ridx = c - run*112;
            const short* src = Wm + ((size_t)(ks*12 + run)*NTF + nbase + ridx)*8;
            gload16(src, &Bbuf[b][c*8]);
        }
    };

    // per-(mf,kh) A validity + LDS byte-chunk offsets (hoisted)
    bool vmask[4][3];
    int  aoff[4][3];
    #pragma unroll
    for (int mf=0; mf<4; ++mf){
        int mrow = wv*64 + mf*16 + l16;
        int m6 = (m0 + mrow) % 6;
        #pragma unroll
        for (int kh=0; kh<3; ++kh){
            int hh = m6 + kh - 1;
            vmask[mf][kh] = (hh >= 0) && (hh < 6);
            aoff[mf][kh]  = (q*ROWS + mrow + kh)*8;   // lds row r = global row m0-1+r
        }
    }

    floatx4 acc[4][7];
    #pragma unroll
    for (int a=0;a<4;++a)
      #pragma unroll
      for (int b=0;b<7;++b)
        #pragma unroll
        for (int r=0;r<4;++r) acc[a][b][r] = 0.f;

    stageA(0, 0); stageB(0, 0);                      // 11 VMEM issues per wave

    for (int ks = 0; ks < KS; ++ks) {
        const int cur = ks & 1;
        if (ks + 1 < KS) {
            stageA(ks+1, cur^1); stageB(ks+1, cur^1);    // 11 more in flight
            asm volatile("s_waitcnt vmcnt(11)" ::: "memory");  // cur's 11 done
        } else {
            asm volatile("s_waitcnt vmcnt(0)" ::: "memory");
        }
        asm volatile("s_barrier" ::: "memory");      // cur buffer ready for all waves

        #pragma unroll
        for (int kh = 0; kh < 3; ++kh) {
            bf16x8 z = {0,0,0,0,0,0,0,0};
            bf16x8 af[4];
            #pragma unroll
            for (int mf=0; mf<4; ++mf){
                bf16x8 a = *(const bf16x8*)(&Abuf[cur][aoff[mf][kh]]);
                af[mf] = vmask[mf][kh] ? a : z;
            }
            const int bbase = (kh*4 + q)*112 + l16;
            #pragma unroll
            for (int nf = 0; nf < 7; ++nf) {
                bf16x8 b = *(const bf16x8*)(&Bbuf[cur][(bbase + nf*16)*8]);
                #pragma unroll
                for (int mf=0; mf<4; ++mf)
                    acc[mf][nf] = __builtin_amdgcn_mfma_f32_16x16x32_bf16(af[mf], b, acc[mf][nf], 0, 0, 0);
            }
        }
        asm volatile("s_barrier" ::: "memory");      // all reads of cur done (WAR for ks+2 staging)
    }

    // epilogue: bias + relu + store bf16 (+ BN partial stats for conv3)
    #pragma unroll
    for (int nf = 0; nf < 7; ++nf) {
        const int col = nbase + nf*16 + l16;
        const float bv = bias[col];
        float s1 = 0.f, s2 = 0.f;
        #pragma unroll
        for (int mf = 0; mf < 4; ++mf) {
            floatx4 v = acc[mf][nf];
            #pragma unroll
            for (int r = 0; r < 4; ++r) {
                float y = fmaxf(v[r] + bv, 0.f);
                const int mg = m0 + wv*64 + mf*16 + q*4 + r; // C/D: row=q*4+r, col=l16
                Out[(size_t)mg*NTF + col] = f2bf(y);
                if (STATS){ s1 += y; s2 += y*y; }
            }
        }
        if (STATS) {
            s1 += __shfl_xor(s1, 16); s1 += __shfl_xor(s1, 32);
            s2 += __shfl_xor(s2, 16); s2 += __shfl_xor(s2, 32);
            if (q == 0 && col < 97) {
                atomicAdd(&sst[0][col], s1);
                atomicAdd(&sst[1][col], s2);
            }
        }
    }
    if (STATS) {
        __syncthreads();
        if (tid < 97) {
            atomicAdd(&stats[tid],     sst[0][tid]);
            atomicAdd(&stats[128+tid], sst[1][tid]);
        }
    }
}

// ---------------- BN (batch stats) + affine + Linear(6,6) + layout transpose ----------------
__global__ __launch_bounds__(256) void final_kernel(
    const short* __restrict__ f3, const float* __restrict__ stats,
    const float* __restrict__ gamma, const float* __restrict__ beta,
    const float* __restrict__ Wl, const float* __restrict__ bl,
    float* __restrict__ out)
{
    const int idx = blockIdx.x*256 + threadIdx.x;  // t*97+n
    const int t = idx / NN;
    const int n = idx - t*NN;
    const float inv_cnt = 1.0f / (float)M_TOT;
    const float mean = stats[n] * inv_cnt;
    const float var  = stats[128+n] * inv_cnt - mean*mean;
    const float rstd = rsqrtf(var + 1e-5f);
    const float ga = gamma[n], be = beta[n];
    float v[6];
    #pragma unroll
    for (int hh=0; hh<6; ++hh) {
        float raw = bf2f(f3[(size_t)(t*6 + hh)*112 + n]);
        v[hh] = (raw - mean)*rstd*ga + be;
    }
    #pragma unroll
    for (int ho=0; ho<6; ++ho) {
        float o = bl[ho];
        #pragma unroll
        for (int hh=0; hh<6; ++hh) o = fmaf(v[hh], Wl[ho*6+hh], o);
        out[(size_t)idx*6 + ho] = o;
    }
}

extern "C" void kernel_launch(void* const* d_in, const int* in_sizes, int n_in,
                              void* d_out, int out_size, void* d_ws, size_t ws_size,
                              hipStream_t stream)
{
    const float* X    = (const float*)d_in[1];
    const float* Wih  = (const float*)d_in[3];
    const float* Whh  = (const float*)d_in[4];
    const float* bih  = (const float*)d_in[5];
    const float* bhh  = (const float*)d_in[6];
    const float* Wc1  = (const float*)d_in[7];
    const float* bc1  = (const float*)d_in[8];
    const float* Wc2  = (const float*)d_in[9];
    const float* bc2  = (const float*)d_in[10];
    const float* Wc3  = (const float*)d_in[11];
    const float* bc3  = (const float*)d_in[12];
    const float* gam  = (const float*)d_in[13];
    const float* bet  = (const float*)d_in[14];
    const float* Wl   = (const float*)d_in[15];
    const float* bl   = (const float*)d_in[16];

    char* ws = (char*)d_ws;
    short* al = (short*)(ws + AL_OFF);
    short* f1 = (short*)(ws + F1_OFF);
    short* f2 = (short*)(ws + F2_OFF);
    short* f3 = (short*)(ws + F3_OFF);
    short* xp = (short*)(ws + XP_OFF);   // aliases f1/f2 (dead before conv1)
    short* w1 = (short*)(ws + W1_OFF);
    short* w2 = (short*)(ws + W2_OFF);
    short* w3 = (short*)(ws + W3_OFF);
    float* b1 = (float*)(ws + B1_OFF);
    float* b2 = (float*)(ws + B2_OFF);
    float* b3 = (float*)(ws + B3_OFF);
    float* st = (float*)(ws + ST_OFF);
    short* zp = (short*)(ws + ZP_OFF);

    hipMemsetAsync(al, 0, AL_SZ, stream);       // zero-pad columns 97..127 of al
    hipMemsetAsync(st, 0, 1024 + 256, stream);  // BN stat accumulators + zero page

    repack_all<<<(RT3+255)/256, 256, 0, stream>>>(Wc1, bc1, w1, b1,
                                                  Wc2, bc2, w2, b2,
                                                  Wc3, bc3, w3, b3);

    xproj_kernel<<<(T_STEPS*NN)/256, 256, 0, stream>>>(X, Wih, bih, bhh, xp);

    lstm_kernel<<<(NCHUNK*NN)/256, 256, 0, stream>>>(xp, Whh, al);

    conv_pipe<128,224,false><<<dim3(M_TOT/256, 2), 256, 0, stream>>>(al, w1, b1, f1, nullptr, zp);
    conv_pipe<224,224,false><<<dim3(M_TOT/256, 2), 256, 0, stream>>>(f1, w2, b2, f2, nullptr, zp);
    conv_pipe<224,112,true ><<<dim3(M_TOT/256, 1), 256, 0, stream>>>(f2, w3, b3, f3, st, zp);

    final_kernel<<<(T_STEPS*NN)/256, 256, 0, stream>>>(f3, st, gam, bet, Wl, bl, (float*)d_out);
}

// Round 8
// 399.341 us; speedup vs baseline: 1.0390x; 1.0390x over previous
//
#include <hip/hip_runtime.h>

#define DI __device__ __forceinline__

using floatx4 = __attribute__((ext_vector_type(4))) float;
using bf16x8  = __attribute__((ext_vector_type(8))) short;
using bf16x4  = __attribute__((ext_vector_type(4))) short;
using uintx4  = __attribute__((ext_vector_type(4))) unsigned int;

constexpr int T_STEPS = 16384;
constexpr int NN      = 97;
constexpr int M_TOT   = T_STEPS * 6;   // 98304 rows of the (t,h) x channel matrices
constexpr int CHUNK   = 16;            // stored steps per chunk (reverted: best work/parallelism tradeoff)
constexpr int WARM    = 12;            // warm-up steps
constexpr int NCHUNK  = T_STEPS / CHUNK;   // 1024

// ---------------- ws layout (bytes, all 256B aligned) ----------------
constexpr size_t AL_OFF = 0;                  constexpr size_t AL_SZ = (size_t)M_TOT*128*2; // al: [M][128] bf16 (97 used, zero-pad)
constexpr size_t F1_OFF = AL_OFF + AL_SZ;     constexpr size_t F1_SZ = (size_t)M_TOT*224*2; // f1: [M][224] bf16 (194 used)
constexpr size_t F2_OFF = F1_OFF + F1_SZ;     constexpr size_t F2_SZ = F1_SZ;
constexpr size_t F3_OFF = F2_OFF + F2_SZ;     constexpr size_t F3_SZ = (size_t)M_TOT*112*2; // f3: [M][112] bf16 (97 used)
constexpr size_t W1_OFF = F3_OFF + F3_SZ;     constexpr size_t W1_SZ = (size_t)3*224*128*2;
constexpr size_t W2_OFF = W1_OFF + W1_SZ;     constexpr size_t W2_SZ = (size_t)3*224*224*2;
constexpr size_t W3_OFF = W2_OFF + W2_SZ;     constexpr size_t W3_SZ = (size_t)3*112*224*2;
constexpr size_t B1_OFF = W3_OFF + W3_SZ;
constexpr size_t B2_OFF = B1_OFF + 1024;
constexpr size_t B3_OFF = B2_OFF + 1024;
constexpr size_t ST_OFF = B3_OFF + 1024;      // stats: [0..96]=sum, [128..224]=sumsq
constexpr size_t ZP_OFF = ST_OFF + 1024;      // 256B zero page (OOB redirect for global_load_lds)
// xp (bf16 [T][97][2][16] = 101.7 MB) aliased onto f1+f2 (177 MB): dead before conv1 writes f1.
constexpr size_t XP_OFF = F1_OFF;

DI short f2bf(float f){
    union { float f; unsigned u; } a; a.f = f;
    unsigned r = (a.u + 0x7FFFu + ((a.u >> 16) & 1u)) >> 16;
    return (short)r;
}
DI float bf2f(short s){
    union { unsigned u; float f; } a; a.u = ((unsigned)(unsigned short)s) << 16;
    return a.f;
}
DI float fsig(float x){
    float e = __builtin_amdgcn_exp2f(x * -1.442695041f);
    return __builtin_amdgcn_rcpf(1.0f + e);
}
DI float ftanh(float x){
    float e = __builtin_amdgcn_exp2f(x * 2.885390082f);   // exp(2x)
    return 1.0f - 2.0f * __builtin_amdgcn_rcpf(e + 1.0f); // graceful at +-inf
}

// async global->LDS, 16B per lane; LDS dest must be wave-uniform base + lane*16
DI void gload16(const void* g, void* l) {
    __builtin_amdgcn_global_load_lds(
        (const __attribute__((address_space(1))) unsigned int*)g,
        (__attribute__((address_space(3))) unsigned int*)l, 16, 0, 0);
}

// ---------------- weight repack (all three convs in one dispatch) ----------------
// layout: Wg[ks][kh][q][n][j]: k = ks*32 + q*8 + j (zero-padded), value = Wc[n][k][kh][kw=1]
DI void repack_one(const float* Wc, const float* bc, short* wdst, float* bdst,
                   int COUT, int CIN, int NT, int i)
{
    int j  = i & 7;
    int t1 = i >> 3;
    int n  = t1 % NT;
    int t2 = t1 / NT;
    int qq = t2 & 3;
    int t3 = t2 >> 2;
    int kh = t3 % 3;
    int ks = t3 / 3;
    int k  = ks*32 + qq*8 + j;
    float v = 0.f;
    if (n < COUT && k < CIN) v = Wc[((n*CIN + k)*3 + kh)*3 + 1]; // kw=1 only (W=1, pad=1)
    wdst[i] = f2bf(v);
    if (i < NT) bdst[i] = (i < COUT) ? bc[i] : 0.f;
}

constexpr int RT1 = 3*224*128;
constexpr int RT2 = RT1 + 3*224*224;
constexpr int RT3 = RT2 + 3*112*224;

__global__ __launch_bounds__(256) void repack_all(
    const float* __restrict__ Wc1, const float* __restrict__ bc1, short* __restrict__ w1, float* __restrict__ b1,
    const float* __restrict__ Wc2, const float* __restrict__ bc2, short* __restrict__ w2, float* __restrict__ b2,
    const float* __restrict__ Wc3, const float* __restrict__ bc3, short* __restrict__ w3, float* __restrict__ b3)
{
    int idx = blockIdx.x*256 + threadIdx.x;
    if (idx < RT1)       repack_one(Wc1, bc1, w1, b1, 194,  97, 224, idx);
    else if (idx < RT2)  repack_one(Wc2, bc2, w2, b2, 194, 194, 224, idx - RT1);
    else if (idx < RT3)  repack_one(Wc3, bc3, w3, b3,  97, 194, 112, idx - RT2);
}

// ---------------- x-projection, permuted for 2-lane LSTM ----------------
// gate g = cls*6 + j (cls: 0=i 1=f 2=g 3=o). Lane parity p owns j = 3p..3p+2.
// store pos = p*16 + cls*3 + (j%3); per-lane row = 16 bf16 (32B, aligned).
__global__ __launch_bounds__(256) void xproj_kernel(
    const float* __restrict__ X, const float* __restrict__ Wih,
    const float* __restrict__ bih, const float* __restrict__ bhh,
    short* __restrict__ xp)
{
    const int idx = blockIdx.x*256 + threadIdx.x;   // t*97+n, exactly T*97 threads
    const floatx4* xv = (const floatx4*)(X + (size_t)idx*12);
    floatx4 x0 = xv[0], x1 = xv[1], x2 = xv[2];
    float xr[12];
    #pragma unroll
    for (int f=0; f<4; ++f){ xr[f]=x0[f]; xr[4+f]=x1[f]; xr[8+f]=x2[f]; }

    short o32[32];
    #pragma unroll
    for (int v=0; v<32; ++v) o32[v] = 0;
    #pragma unroll
    for (int g=0; g<24; ++g) {
        float s = bih[g] + bhh[g];
        #pragma unroll
        for (int f=0; f<12; ++f) s = fmaf(xr[f], Wih[g*12+f], s);
        int j = g % 6, cls = g / 6;
        o32[(j/3)*16 + cls*3 + (j%3)] = f2bf(s);
    }
    uintx4* dst = (uintx4*)(xp + (size_t)idx*32);    // 64B per (t,n)
    #pragma unroll
    for (int v=0; v<4; ++v) dst[v] = *(const uintx4*)(&o32[v*8]);
}

// ---------------- LSTM: 2 lanes per chain (lane parity owns 3 hidden units) ----------------
// chains = 97 nodes x 1024 chunks; 198656 lanes = 776 blocks = ~3 blocks/CU = 3 waves/SIMD.
// Per-lane per step: 12 gates x 6 FMA + 18 transcendental pairs/2; partner h via shfl_xor(1).
__global__ __launch_bounds__(256, 3) void lstm_kernel(
    const short* __restrict__ xp, const float* __restrict__ Whh,
    short* __restrict__ al)
{
    const int u     = blockIdx.x*256 + threadIdx.x;   // 0..198655
    const int p     = u & 1;
    const int chain = u >> 1;                         // 0..99327
    const int n  = chain % NN;
    const int ch = chain / NN;                        // 0..1023
    const int ts = ch*CHUNK;
    const int te = ts + CHUNK;
    int t0 = ts - WARM; if (t0 < 0) t0 = 0;           // ch 0 starts exactly from the true init

    // per-lane weight slices: gate c (0..11) -> global gate g = cls*6 + 3p + jl
    float wA[12][3], wB[12][3];                       // own-h cols, partner-h cols
    #pragma unroll
    for (int c=0; c<12; ++c) {
        int cls = c/3, jl = c - cls*3;
        const float* row = Whh + (cls*6 + 3*p + jl)*6;
        #pragma unroll
        for (int d=0; d<3; ++d) { wA[c][d] = row[3*p + d]; wB[c][d] = row[3*(1-p) + d]; }
    }

    float hA[3] = {0.f,0.f,0.f};   // own h (j = 3p+jl)
    float hB[3] = {0.f,0.f,0.f};   // partner h
    float cs[3] = {0.f,0.f,0.f};

    for (int t = t0; t < te; ++t) {
        const short* xrow = xp + ((size_t)(t*NN + n)*2 + p)*16;
        uintx4 q0 = *(const uintx4*)xrow;                          // c = 0..7
        unsigned long long q1 = *(const unsigned long long*)(xrow + 8); // c = 8..11
        bf16x8 b0 = __builtin_bit_cast(bf16x8, q0);
        bf16x4 b1 = __builtin_bit_cast(bf16x4, q1);
        float xr[12];
        #pragma unroll
        for (int f=0; f<8; ++f) xr[f] = bf2f(b0[f]);
        #pragma unroll
        for (int f=0; f<4; ++f) xr[8+f] = bf2f(b1[f]);

        float gg[12];
        #pragma unroll
        for (int c=0; c<12; ++c) {
            float s = xr[c];
            #pragma unroll
            for (int d=0; d<3; ++d) s = fmaf(hA[d], wA[c][d], s);
            #pragma unroll
            for (int d=0; d<3; ++d) s = fmaf(hB[d], wB[c][d], s);
            gg[c] = s;
        }
        #pragma unroll
        for (int jl=0; jl<3; ++jl) {
            float ig = fsig(gg[jl]);
            float fg = fsig(gg[3+jl]);
            float cg = ftanh(gg[6+jl]);
            float og = fsig(gg[9+jl]);
            cs[jl] = fmaf(fg, cs[jl], ig*cg);
            hA[jl] = ftanh(og * ftanh(cs[jl]));        // extra tanh, fed back (matches ref)
        }
        #pragma unroll
        for (int jl=0; jl<3; ++jl) hB[jl] = __shfl_xor(hA[jl], 1);

        if (t >= ts) {
            int base = (t*6 + 3*p)*128 + n;            // A[m=(t,j)][k=n], stride 128
            #pragma unroll
            for (int jl=0; jl<3; ++jl) al[base + jl*128] = f2bf(hA[jl]);
        }
    }
}

// ---------------- pipelined conv as 3-tap (kh) GEMM, bf16 MFMA 16x16x32 ----------------
// Block = 256 thr (4 waves), tile 256 rows x 112 cols (N split via blockIdx.y for NT=224).
// Wave owns 64 rows (mf=4) x 112 cols (nf=7). Double-buffered A+B LDS; stage(ks+1)
// issued before waiting on ks via raw s_waitcnt vmcnt(11) (11 vmem issues per wave
// per k-step, tails duplicated across all 4 waves to keep counts wave-uniform)
// + raw s_barrier. 78.7 KB LDS -> 2 blocks/CU = 8 waves/CU = 2 waves/SIMD.
template<int KP, int NTF, bool STATS>
__global__ __launch_bounds__(256) void conv_pipe(
    const short* __restrict__ In, const short* __restrict__ Wm,
    const float* __restrict__ bias, short* __restrict__ Out,
    float* __restrict__ stats, const short* __restrict__ zp)
{
    constexpr int KS   = KP/32;
    constexpr int ROWS = 258;            // 256 + +-1 halo
    constexpr int ACHR = 4*ROWS;         // 1032 real A chunks (pad to 1088)
    __shared__ alignas(16) short Abuf[2][1088*8];   // 34.8 KB
    __shared__ alignas(16) short Bbuf[2][1344*8];   // 43.0 KB
    __shared__ float sst[2][112];

    const int tid   = threadIdx.x;
    const int lane  = tid & 63;
    const int wv    = tid >> 6;
    const int l16   = lane & 15;
    const int q     = lane >> 4;
    const int m0    = blockIdx.x * 256;
    const int nbase = blockIdx.y * 112;

    if (STATS && tid < 112){ sst[0][tid]=0.f; sst[1][tid]=0.f; }

    auto stageA = [&](int ks, int b) {
        const int k0 = ks*32;
        #pragma unroll
        for (int it=0; it<4; ++it) {                 // chunks 0..1023 (all real)
            int c  = it*256 + tid;
            int cq = c / ROWS;
            int cr = c - cq*ROWS;
            int mg = m0 - 1 + cr;
            const short* src = (mg >= 0 && mg < M_TOT) ? In + (size_t)mg*KP + k0 + cq*8 : zp;
            gload16(src, &Abuf[b][c*8]);
        }
        {                                            // tail 1024..1087, all 4 waves (dup ok)
            int c  = 1024 + (tid & 63);
            const short* src = zp;
            if (c < ACHR) {                          // real only for c < 1032 (cq==3)
                int cr = c - 3*ROWS;
                int mg = m0 - 1 + cr;
                if (mg >= 0 && mg < M_TOT) src = In + (size_t)mg*KP + k0 + 3*8;
            }
            gload16(src, &Abuf[b][c*8]);
        }
    };
    auto stageB = [&](int ks, int b) {
        #pragma unroll
        for (int it=0; it<5; ++it) {                 // chunks 0..1279
            int c    = it*256 + tid;
            int run  = c / 112;
            int ridx = c - run*112;
            const short* src = Wm + ((size_t)(ks*12 + run)*NTF + nbase + ridx)*8;
            gload16(src, &Bbuf[b][c*8]);
        }
        {                                            // tail 1280..1343, all 4 waves (dup ok)
            int c    = 1280 + (tid & 63);
            int run  = c / 112;
            int ridx = c - run*112;
            const short* src = Wm + ((size_t)(ks*12 + run)*NTF + nbase + ridx)*8;
            gload16(src, &Bbuf[b][c*8]);
        }
    };

    // per-(mf,kh) A validity + LDS byte-chunk offsets (hoisted)
    bool vmask[4][3];
    int  aoff[4][3];
    #pragma unroll
    for (int mf=0; mf<4; ++mf){
        int mrow = wv*64 + mf*16 + l16;
        int m6 = (m0 + mrow) % 6;
        #pragma unroll
        for (int kh=0; kh<3; ++kh){
            int hh = m6 + kh - 1;
            vmask[mf][kh] = (hh >= 0) && (hh < 6);
            aoff[mf][kh]  = (q*ROWS + mrow + kh)*8;   // lds row r = global row m0-1+r
        }
    }

    floatx4 acc[4][7];
    #pragma unroll
    for (int a=0;a<4;++a)
      #pragma unroll
      for (int b=0;b<7;++b)
        #pragma unroll
        for (int r=0;r<4;++r) acc[a][b][r] = 0.f;

    stageA(0, 0); stageB(0, 0);                      // 11 VMEM issues per wave

    for (int ks = 0; ks < KS; ++ks) {
        const int cur = ks & 1;
        if (ks + 1 < KS) {
            stageA(ks+1, cur^1); stageB(ks+1, cur^1);    // 11 more in flight
            asm volatile("s_waitcnt vmcnt(11)" ::: "memory");  // cur's 11 done
        } else {
            asm volatile("s_waitcnt vmcnt(0)" ::: "memory");
        }
        asm volatile("s_barrier" ::: "memory");      // cur buffer ready for all waves

        #pragma unroll
        for (int kh = 0; kh < 3; ++kh) {
            bf16x8 z = {0,0,0,0,0,0,0,0};
            bf16x8 af[4];
            #pragma unroll
            for (int mf=0; mf<4; ++mf){
                bf16x8 a = *(const bf16x8*)(&Abuf[cur][aoff[mf][kh]]);
                af[mf] = vmask[mf][kh] ? a : z;
            }
            const int bbase = (kh*4 + q)*112 + l16;
            #pragma unroll
            for (int nf = 0; nf < 7; ++nf) {
                bf16x8 b = *(const bf16x8*)(&Bbuf[cur][(bbase + nf*16)*8]);
                #pragma unroll
                for (int mf=0; mf<4; ++mf)
                    acc[mf][nf] = __builtin_amdgcn_mfma_f32_16x16x32_bf16(af[mf], b, acc[mf][nf], 0, 0, 0);
            }
        }
        asm volatile("s_barrier" ::: "memory");      // all reads of cur done (WAR for ks+2 staging)
    }

    // epilogue: bias + relu + store bf16 (+ BN partial stats for conv3)
    #pragma unroll
    for (int nf = 0; nf < 7; ++nf) {
        const int col = nbase + nf*16 + l16;
        const float bv = bias[col];
        float s1 = 0.f, s2 = 0.f;
        #pragma unroll
        for (int mf = 0; mf < 4; ++mf) {
            floatx4 v = acc[mf][nf];
            #pragma unroll
            for (int r = 0; r < 4; ++r) {
                float y = fmaxf(v[r] + bv, 0.f);
                const int mg = m0 + wv*64 + mf*16 + q*4 + r; // C/D: row=q*4+r, col=l16
                Out[(size_t)mg*NTF + col] = f2bf(y);
                if (STATS){ s1 += y; s2 += y*y; }
            }
        }
        if (STATS) {
            s1 += __shfl_xor(s1, 16); s1 += __shfl_xor(s1, 32);
            s2 += __shfl_xor(s2, 16); s2 += __shfl_xor(s2, 32);
            if (q == 0 && col < 97) {
                atomicAdd(&sst[0][col], s1);
                atomicAdd(&sst[1][col], s2);
            }
        }
    }
    if (STATS) {
        __syncthreads();
        if (tid < 97) {
            atomicAdd(&stats[tid],     sst[0][tid]);
            atomicAdd(&stats[128+tid], sst[1][tid]);
        }
    }
}

// ---------------- BN (batch stats) + affine + Linear(6,6) + layout transpose ----------------
__global__ __launch_bounds__(256) void final_kernel(
    const short* __restrict__ f3, const float* __restrict__ stats,
    const float* __restrict__ gamma, const float* __restrict__ beta,
    const float* __restrict__ Wl, const float* __restrict__ bl,
    float* __restrict__ out)
{
    const int idx = blockIdx.x*256 + threadIdx.x;  // t*97+n
    const int t = idx / NN;
    const int n = idx - t*NN;
    const float inv_cnt = 1.0f / (float)M_TOT;
    const float mean = stats[n] * inv_cnt;
    const float var  = stats[128+n] * inv_cnt - mean*mean;
    const float rstd = rsqrtf(var + 1e-5f);
    const float ga = gamma[n], be = beta[n];
    float v[6];
    #pragma unroll
    for (int hh=0; hh<6; ++hh) {
        float raw = bf2f(f3[(size_t)(t*6 + hh)*112 + n]);
        v[hh] = (raw - mean)*rstd*ga + be;
    }
    #pragma unroll
    for (int ho=0; ho<6; ++ho) {
        float o = bl[ho];
        #pragma unroll
        for (int hh=0; hh<6; ++hh) o = fmaf(v[hh], Wl[ho*6+hh], o);
        out[(size_t)idx*6 + ho] = o;
    }
}

extern "C" void kernel_launch(void* const* d_in, const int* in_sizes, int n_in,
                              void* d_out, int out_size, void* d_ws, size_t ws_size,
                              hipStream_t stream)
{
    const float* X    = (const float*)d_in[1];
    const float* Wih  = (const float*)d_in[3];
    const float* Whh  = (const float*)d_in[4];
    const float* bih  = (const float*)d_in[5];
    const float* bhh  = (const float*)d_in[6];
    const float* Wc1  = (const float*)d_in[7];
    const float* bc1  = (const float*)d_in[8];
    const float* Wc2  = (const float*)d_in[9];
    const float* bc2  = (const float*)d_in[10];
    const float* Wc3  = (const float*)d_in[11];
    const float* bc3  = (const float*)d_in[12];
    const float* gam  = (const float*)d_in[13];
    const float* bet  = (const float*)d_in[14];
    const float* Wl   = (const float*)d_in[15];
    const float* bl   = (const float*)d_in[16];

    char* ws = (char*)d_ws;
    short* al = (short*)(ws + AL_OFF);
    short* f1 = (short*)(ws + F1_OFF);
    short* f2 = (short*)(ws + F2_OFF);
    short* f3 = (short*)(ws + F3_OFF);
    short* xp = (short*)(ws + XP_OFF);   // aliases f1/f2 (dead before conv1)
    short* w1 = (short*)(ws + W1_OFF);
    short* w2 = (short*)(ws + W2_OFF);
    short* w3 = (short*)(ws + W3_OFF);
    float* b1 = (float*)(ws + B1_OFF);
    float* b2 = (float*)(ws + B2_OFF);
    float* b3 = (float*)(ws + B3_OFF);
    float* st = (float*)(ws + ST_OFF);
    short* zp = (short*)(ws + ZP_OFF);

    hipMemsetAsync(al, 0, AL_SZ, stream);       // zero-pad columns 97..127 of al
    hipMemsetAsync(st, 0, 1024 + 256, stream);  // BN stat accumulators + zero page

    repack_all<<<(RT3+255)/256, 256, 0, stream>>>(Wc1, bc1, w1, b1,
                                                  Wc2, bc2, w2, b2,
                                                  Wc3, bc3, w3, b3);

    xproj_kernel<<<(T_STEPS*NN)/256, 256, 0, stream>>>(X, Wih, bih, bhh, xp);

    lstm_kernel<<<(NCHUNK*NN*2)/256, 256, 0, stream>>>(xp, Whh, al);

    conv_pipe<128,224,false><<<dim3(M_TOT/256, 2), 256, 0, stream>>>(al, w1, b1, f1, nullptr, zp);
    conv_pipe<224,224,false><<<dim3(M_TOT/256, 2), 256, 0, stream>>>(f1, w2, b2, f2, nullptr, zp);
    conv_pipe<224,112,true ><<<dim3(M_TOT/256, 1), 256, 0, stream>>>(f2, w3, b3, f3, st, zp);

    final_kernel<<<(T_STEPS*NN)/256, 256, 0, stream>>>(f3, st, gam, bet, Wl, bl, (float*)d_out);
}

// Round 9
// 381.092 us; speedup vs baseline: 1.0888x; 1.0479x over previous
//
#include <hip/hip_runtime.h>

#define DI __device__ __forceinline__

using floatx4 = __attribute__((ext_vector_type(4))) float;
using bf16x8  = __attribute__((ext_vector_type(8))) short;
using bf16x4  = __attribute__((ext_vector_type(4))) short;
using uintx4  = __attribute__((ext_vector_type(4))) unsigned int;

constexpr int T_STEPS = 16384;
constexpr int NN      = 97;
constexpr int M_TOT   = T_STEPS * 6;   // 98304 rows of the (t,h) x channel matrices
constexpr int CHUNK   = 16;            // stored steps per chunk
constexpr int WARM    = 12;            // warm-up steps
constexpr int NCHUNK  = T_STEPS / CHUNK;   // 1024

// ---------------- ws layout (bytes, all 256B aligned) ----------------
constexpr size_t AL_OFF = 0;                  constexpr size_t AL_SZ = (size_t)M_TOT*128*2; // al: [M][128] bf16 (97 used, zero-pad)
constexpr size_t F1_OFF = AL_OFF + AL_SZ;     constexpr size_t F1_SZ = (size_t)M_TOT*224*2; // f1: [M][224] bf16 (194 used)
constexpr size_t F2_OFF = F1_OFF + F1_SZ;     constexpr size_t F2_SZ = F1_SZ;
constexpr size_t F3_OFF = F2_OFF + F2_SZ;     constexpr size_t F3_SZ = (size_t)M_TOT*112*2; // f3: [M][112] bf16 (97 used)
constexpr size_t W1_OFF = F3_OFF + F3_SZ;     constexpr size_t W1_SZ = (size_t)3*224*128*2;
constexpr size_t W2_OFF = W1_OFF + W1_SZ;     constexpr size_t W2_SZ = (size_t)3*224*224*2;
constexpr size_t W3_OFF = W2_OFF + W2_SZ;     constexpr size_t W3_SZ = (size_t)3*112*224*2;
constexpr size_t B1_OFF = W3_OFF + W3_SZ;
constexpr size_t B2_OFF = B1_OFF + 1024;
constexpr size_t B3_OFF = B2_OFF + 1024;
constexpr size_t ST_OFF = B3_OFF + 1024;      // stats: [0..96]=sum, [128..224]=sumsq
constexpr size_t ZP_OFF = ST_OFF + 1024;      // 256B zero page (OOB redirect for global_load_lds)
// xp (bf16 [T][97][2][12] = 76.3 MB) aliased onto f1+f2 (177 MB): dead before conv1 writes f1.
constexpr size_t XP_OFF = F1_OFF;

DI short f2bf(float f){
    union { float f; unsigned u; } a; a.f = f;
    unsigned r = (a.u + 0x7FFFu + ((a.u >> 16) & 1u)) >> 16;
    return (short)r;
}
DI float bf2f(short s){
    union { unsigned u; float f; } a; a.u = ((unsigned)(unsigned short)s) << 16;
    return a.f;
}
DI float fsig(float x){
    float e = __builtin_amdgcn_exp2f(x * -1.442695041f);
    return __builtin_amdgcn_rcpf(1.0f + e);
}
DI float ftanh(float x){
    float e = __builtin_amdgcn_exp2f(x * 2.885390082f);   // exp(2x)
    return 1.0f - 2.0f * __builtin_amdgcn_rcpf(e + 1.0f); // graceful at +-inf
}

// async global->LDS, 16B per lane; LDS dest must be wave-uniform base + lane*16
DI void gload16(const void* g, void* l) {
    __builtin_amdgcn_global_load_lds(
        (const __attribute__((address_space(1))) unsigned int*)g,
        (__attribute__((address_space(3))) unsigned int*)l, 16, 0, 0);
}

// ---------------- weight repack (all three convs in one dispatch) ----------------
// layout: Wg[ks][kh][q][n][j]: k = ks*32 + q*8 + j (zero-padded), value = Wc[n][k][kh][kw=1]
DI void repack_one(const float* Wc, const float* bc, short* wdst, float* bdst,
                   int COUT, int CIN, int NT, int i)
{
    int j  = i & 7;
    int t1 = i >> 3;
    int n  = t1 % NT;
    int t2 = t1 / NT;
    int qq = t2 & 3;
    int t3 = t2 >> 2;
    int kh = t3 % 3;
    int ks = t3 / 3;
    int k  = ks*32 + qq*8 + j;
    float v = 0.f;
    if (n < COUT && k < CIN) v = Wc[((n*CIN + k)*3 + kh)*3 + 1]; // kw=1 only (W=1, pad=1)
    wdst[i] = f2bf(v);
    if (i < NT) bdst[i] = (i < COUT) ? bc[i] : 0.f;
}

constexpr int RT1 = 3*224*128;
constexpr int RT2 = RT1 + 3*224*224;
constexpr int RT3 = RT2 + 3*112*224;

__global__ __launch_bounds__(256) void repack_all(
    const float* __restrict__ Wc1, const float* __restrict__ bc1, short* __restrict__ w1, float* __restrict__ b1,
    const float* __restrict__ Wc2, const float* __restrict__ bc2, short* __restrict__ w2, float* __restrict__ b2,
    const float* __restrict__ Wc3, const float* __restrict__ bc3, short* __restrict__ w3, float* __restrict__ b3)
{
    int idx = blockIdx.x*256 + threadIdx.x;
    if (idx < RT1)       repack_one(Wc1, bc1, w1, b1, 194,  97, 224, idx);
    else if (idx < RT2)  repack_one(Wc2, bc2, w2, b2, 194, 194, 224, idx - RT1);
    else if (idx < RT3)  repack_one(Wc3, bc3, w3, b3,  97, 194, 112, idx - RT2);
}

// ---------------- x-projection, permuted for 2-lane LSTM, LDS-staged coalesced stores ----
// gate g = cls*6 + j (cls: 0=i 1=f 2=g 3=o). Lane parity p owns j = 3p..3p+2.
// row = 24 bf16 (48B): pos = p*12 + cls*3 + (j%3). Block output (12 KB) staged in LDS,
// written back as one lane-contiguous 16B/lane stream (fixes 4x partial-line stores).
__global__ __launch_bounds__(256) void xproj_kernel(
    const float* __restrict__ X, const float* __restrict__ Wih,
    const float* __restrict__ bih, const float* __restrict__ bhh,
    short* __restrict__ xp)
{
    __shared__ alignas(16) short sbuf[256*24];      // 12 KB
    const int tid = threadIdx.x;
    const int idx = blockIdx.x*256 + tid;           // t*97+n, exactly T*97 threads
    const floatx4* xv = (const floatx4*)(X + (size_t)idx*12);
    floatx4 x0 = xv[0], x1 = xv[1], x2 = xv[2];
    float xr[12];
    #pragma unroll
    for (int f=0; f<4; ++f){ xr[f]=x0[f]; xr[4+f]=x1[f]; xr[8+f]=x2[f]; }

    short o24[24];
    #pragma unroll
    for (int g=0; g<24; ++g) {
        float s = bih[g] + bhh[g];
        #pragma unroll
        for (int f=0; f<12; ++f) s = fmaf(xr[f], Wih[g*12+f], s);
        int j = g % 6, cls = g / 6;
        o24[(j/3)*12 + cls*3 + (j%3)] = f2bf(s);
    }
    #pragma unroll
    for (int k=0; k<3; ++k)
        *(uintx4*)(&sbuf[tid*24 + k*8]) = *(const uintx4*)(&o24[k*8]);
    __syncthreads();
    const size_t base = (size_t)blockIdx.x * (256*24);
    #pragma unroll
    for (int k=0; k<3; ++k) {
        int off = k*2048 + tid*8;                   // shorts; 16B per lane, contiguous
        *(uintx4*)(xp + base + off) = *(const uintx4*)(&sbuf[off]);
    }
}

// ---------------- LSTM: 2 lanes per chain (lane parity owns 3 hidden units) ----------------
// chains = 97 nodes x 1024 chunks; 198656 lanes = 776 blocks = ~3 blocks/CU = 3 waves/SIMD.
__global__ __launch_bounds__(256, 3) void lstm_kernel(
    const short* __restrict__ xp, const float* __restrict__ Whh,
    short* __restrict__ al)
{
    const int u     = blockIdx.x*256 + threadIdx.x;   // 0..198655
    const int p     = u & 1;
    const int chain = u >> 1;                         // 0..99327
    const int n  = chain % NN;
    const int ch = chain / NN;                        // 0..1023
    const int ts = ch*CHUNK;
    const int te = ts + CHUNK;
    int t0 = ts - WARM; if (t0 < 0) t0 = 0;           // ch 0 starts exactly from the true init

    // per-lane weight slices: gate c (0..11) -> global gate g = cls*6 + 3p + jl
    float wA[12][3], wB[12][3];                       // own-h cols, partner-h cols
    #pragma unroll
    for (int c=0; c<12; ++c) {
        int cls = c/3, jl = c - cls*3;
        const float* row = Whh + (cls*6 + 3*p + jl)*6;
        #pragma unroll
        for (int d=0; d<3; ++d) { wA[c][d] = row[3*p + d]; wB[c][d] = row[3*(1-p) + d]; }
    }

    float hA[3] = {0.f,0.f,0.f};   // own h (j = 3p+jl)
    float hB[3] = {0.f,0.f,0.f};   // partner h
    float cs[3] = {0.f,0.f,0.f};

    for (int t = t0; t < te; ++t) {
        const short* xrow = xp + ((size_t)(t*NN + n)*2 + p)*12;   // 24B per lane, 8B aligned
        unsigned long long d0 = *(const unsigned long long*)(xrow);
        unsigned long long d1 = *(const unsigned long long*)(xrow + 4);
        unsigned long long d2 = *(const unsigned long long*)(xrow + 8);
        bf16x4 b0 = __builtin_bit_cast(bf16x4, d0);
        bf16x4 b1 = __builtin_bit_cast(bf16x4, d1);
        bf16x4 b2 = __builtin_bit_cast(bf16x4, d2);
        float xr[12];
        #pragma unroll
        for (int f=0; f<4; ++f){ xr[f]=bf2f(b0[f]); xr[4+f]=bf2f(b1[f]); xr[8+f]=bf2f(b2[f]); }

        float gg[12];
        #pragma unroll
        for (int c=0; c<12; ++c) {
            float s = xr[c];
            #pragma unroll
            for (int d=0; d<3; ++d) s = fmaf(hA[d], wA[c][d], s);
            #pragma unroll
            for (int d=0; d<3; ++d) s = fmaf(hB[d], wB[c][d], s);
            gg[c] = s;
        }
        #pragma unroll
        for (int jl=0; jl<3; ++jl) {
            float ig = fsig(gg[jl]);
            float fg = fsig(gg[3+jl]);
            float cg = ftanh(gg[6+jl]);
            float og = fsig(gg[9+jl]);
            cs[jl] = fmaf(fg, cs[jl], ig*cg);
            hA[jl] = ftanh(og * ftanh(cs[jl]));        // extra tanh, fed back (matches ref)
        }
        #pragma unroll
        for (int jl=0; jl<3; ++jl) hB[jl] = __shfl_xor(hA[jl], 1);

        if (t >= ts) {
            int base = (t*6 + 3*p)*128 + n;            // A[m=(t,j)][k=n], stride 128
            #pragma unroll
            for (int jl=0; jl<3; ++jl) al[base + jl*128] = f2bf(hA[jl]);
        }
    }
}

// ---------------- pipelined conv as 3-tap (kh) GEMM, bf16 MFMA 16x16x32 ----------------
// Block = 256 thr (4 waves), tile 256 rows x 112 cols (N split via blockIdx.y for NT=224).
// Wave owns 64 rows (mf=4) x 112 cols (nf=7). Double-buffered A+B LDS; stage(ks+1)
// issued before waiting on ks via raw s_waitcnt vmcnt(11) (11 vmem issues per wave
// per k-step, tails duplicated across all 4 waves to keep counts wave-uniform)
// + raw s_barrier. 78.7 KB LDS -> 2 blocks/CU = 8 waves/CU = 2 waves/SIMD.
template<int KP, int NTF, bool STATS>
__global__ __launch_bounds__(256) void conv_pipe(
    const short* __restrict__ In, const short* __restrict__ Wm,
    const float* __restrict__ bias, short* __restrict__ Out,
    float* __restrict__ stats, const short* __restrict__ zp)
{
    constexpr int KS   = KP/32;
    constexpr int ROWS = 258;            // 256 + +-1 halo
    constexpr int ACHR = 4*ROWS;         // 1032 real A chunks (pad to 1088)
    __shared__ alignas(16) short Abuf[2][1088*8];   // 34.8 KB
    __shared__ alignas(16) short Bbuf[2][1344*8];   // 43.0 KB
    __shared__ float sst[2][112];

    const int tid   = threadIdx.x;
    const int lane  = tid & 63;
    const int wv    = tid >> 6;
    const int l16   = lane & 15;
    const int q     = lane >> 4;
    const int m0    = blockIdx.x * 256;
    const int nbase = blockIdx.y * 112;

    if (STATS && tid < 112){ sst[0][tid]=0.f; sst[1][tid]=0.f; }

    auto stageA = [&](int ks, int b) {
        const int k0 = ks*32;
        #pragma unroll
        for (int it=0; it<4; ++it) {                 // chunks 0..1023 (all real)
            int c  = it*256 + tid;
            int cq = c / ROWS;
            int cr = c - cq*ROWS;
            int mg = m0 - 1 + cr;
            const short* src = (mg >= 0 && mg < M_TOT) ? In + (size_t)mg*KP + k0 + cq*8 : zp;
            gload16(src, &Abuf[b][c*8]);
        }
        {                                            // tail 1024..1087, all 4 waves (dup ok)
            int c  = 1024 + (tid & 63);
            const short* src = zp;
            if (c < ACHR) {                          // real only for c < 1032 (cq==3)
                int cr = c - 3*ROWS;
                int mg = m0 - 1 + cr;
                if (mg >= 0 && mg < M_TOT) src = In + (size_t)mg*KP + k0 + 3*8;
            }
            gload16(src, &Abuf[b][c*8]);
        }
    };
    auto stageB = [&](int ks, int b) {
        #pragma unroll
        for (int it=0; it<5; ++it) {                 // chunks 0..1279
            int c    = it*256 + tid;
            int run  = c / 112;
            int ridx = c - run*112;
            const short* src = Wm + ((size_t)(ks*12 + run)*NTF + nbase + ridx)*8;
            gload16(src, &Bbuf[b][c*8]);
        }
        {                                            // tail 1280..1343, all 4 waves (dup ok)
            int c    = 1280 + (tid & 63);
            int run  = c / 112;
            int ridx = c - run*112;
            const short* src = Wm + ((size_t)(ks*12 + run)*NTF + nbase + ridx)*8;
            gload16(src, &Bbuf[b][c*8]);
        }
    };

    // per-(mf,kh) A validity + LDS byte-chunk offsets (hoisted)
    bool vmask[4][3];
    int  aoff[4][3];
    #pragma unroll
    for (int mf=0; mf<4; ++mf){
        int mrow = wv*64 + mf*16 + l16;
        int m6 = (m0 + mrow) % 6;
        #pragma unroll
        for (int kh=0; kh<3; ++kh){
            int hh = m6 + kh - 1;
            vmask[mf][kh] = (hh >= 0) && (hh < 6);
            aoff[mf][kh]  = (q*ROWS + mrow + kh)*8;   // lds row r = global row m0-1+r
        }
    }

    floatx4 acc[4][7];
    #pragma unroll
    for (int a=0;a<4;++a)
      #pragma unroll
      for (int b=0;b<7;++b)
        #pragma unroll
        for (int r=0;r<4;++r) acc[a][b][r] = 0.f;

    stageA(0, 0); stageB(0, 0);                      // 11 VMEM issues per wave

    for (int ks = 0; ks < KS; ++ks) {
        const int cur = ks & 1;
        if (ks + 1 < KS) {
            stageA(ks+1, cur^1); stageB(ks+1, cur^1);    // 11 more in flight
            asm volatile("s_waitcnt vmcnt(11)" ::: "memory");  // cur's 11 done
        } else {
            asm volatile("s_waitcnt vmcnt(0)" ::: "memory");
        }
        asm volatile("s_barrier" ::: "memory");      // cur buffer ready for all waves

        #pragma unroll
        for (int kh = 0; kh < 3; ++kh) {
            bf16x8 z = {0,0,0,0,0,0,0,0};
            bf16x8 af[4];
            #pragma unroll
            for (int mf=0; mf<4; ++mf){
                bf16x8 a = *(const bf16x8*)(&Abuf[cur][aoff[mf][kh]]);
                af[mf] = vmask[mf][kh] ? a : z;
            }
            const int bbase = (kh*4 + q)*112 + l16;
            #pragma unroll
            for (int nf = 0; nf < 7; ++nf) {
                bf16x8 b = *(const bf16x8*)(&Bbuf[cur][(bbase + nf*16)*8]);
                #pragma unroll
                for (int mf=0; mf<4; ++mf)
                    acc[mf][nf] = __builtin_amdgcn_mfma_f32_16x16x32_bf16(af[mf], b, acc[mf][nf], 0, 0, 0);
            }
        }
        asm volatile("s_barrier" ::: "memory");      // all reads of cur done (WAR for ks+2 staging)
    }

    // epilogue: bias + relu + store bf16 (+ BN partial stats for conv3)
    #pragma unroll
    for (int nf = 0; nf < 7; ++nf) {
        const int col = nbase + nf*16 + l16;
        const float bv = bias[col];
        float s1 = 0.f, s2 = 0.f;
        #pragma unroll
        for (int mf = 0; mf < 4; ++mf) {
            floatx4 v = acc[mf][nf];
            #pragma unroll
            for (int r = 0; r < 4; ++r) {
                float y = fmaxf(v[r] + bv, 0.f);
                const int mg = m0 + wv*64 + mf*16 + q*4 + r; // C/D: row=q*4+r, col=l16
                Out[(size_t)mg*NTF + col] = f2bf(y);
                if (STATS){ s1 += y; s2 += y*y; }
            }
        }
        if (STATS) {
            s1 += __shfl_xor(s1, 16); s1 += __shfl_xor(s1, 32);
            s2 += __shfl_xor(s2, 16); s2 += __shfl_xor(s2, 32);
            if (q == 0 && col < 97) {
                atomicAdd(&sst[0][col], s1);
                atomicAdd(&sst[1][col], s2);
            }
        }
    }
    if (STATS) {
        __syncthreads();
        if (tid < 97) {
            atomicAdd(&stats[tid],     sst[0][tid]);
            atomicAdd(&stats[128+tid], sst[1][tid]);
        }
    }
}

// ---------------- BN (batch stats) + affine + Linear(6,6) + layout transpose ----------------
__global__ __launch_bounds__(256) void final_kernel(
    const short* __restrict__ f3, const float* __restrict__ stats,
    const float* __restrict__ gamma, const float* __restrict__ beta,
    const float* __restrict__ Wl, const float* __restrict__ bl,
    float* __restrict__ out)
{
    const int idx = blockIdx.x*256 + threadIdx.x;  // t*97+n
    const int t = idx / NN;
    const int n = idx - t*NN;
    const float inv_cnt = 1.0f / (float)M_TOT;
    const float mean = stats[n] * inv_cnt;
    const float var  = stats[128+n] * inv_cnt - mean*mean;
    const float rstd = rsqrtf(var + 1e-5f);
    const float ga = gamma[n], be = beta[n];
    float v[6];
    #pragma unroll
    for (int hh=0; hh<6; ++hh) {
        float raw = bf2f(f3[(size_t)(t*6 + hh)*112 + n]);
        v[hh] = (raw - mean)*rstd*ga + be;
    }
    #pragma unroll
    for (int ho=0; ho<6; ++ho) {
        float o = bl[ho];
        #pragma unroll
        for (int hh=0; hh<6; ++hh) o = fmaf(v[hh], Wl[ho*6+hh], o);
        out[(size_t)idx*6 + ho] = o;
    }
}

extern "C" void kernel_launch(void* const* d_in, const int* in_sizes, int n_in,
                              void* d_out, int out_size, void* d_ws, size_t ws_size,
                              hipStream_t stream)
{
    const float* X    = (const float*)d_in[1];
    const float* Wih  = (const float*)d_in[3];
    const float* Whh  = (const float*)d_in[4];
    const float* bih  = (const float*)d_in[5];
    const float* bhh  = (const float*)d_in[6];
    const float* Wc1  = (const float*)d_in[7];
    const float* bc1  = (const float*)d_in[8];
    const float* Wc2  = (const float*)d_in[9];
    const float* bc2  = (const float*)d_in[10];
    const float* Wc3  = (const float*)d_in[11];
    const float* bc3  = (const float*)d_in[12];
    const float* gam  = (const float*)d_in[13];
    const float* bet  = (const float*)d_in[14];
    const float* Wl   = (const float*)d_in[15];
    const float* bl   = (const float*)d_in[16];

    char* ws = (char*)d_ws;
    short* al = (short*)(ws + AL_OFF);
    short* f1 = (short*)(ws + F1_OFF);
    short* f2 = (short*)(ws + F2_OFF);
    short* f3 = (short*)(ws + F3_OFF);
    short* xp = (short*)(ws + XP_OFF);   // aliases f1/f2 (dead before conv1)
    short* w1 = (short*)(ws + W1_OFF);
    short* w2 = (short*)(ws + W2_OFF);
    short* w3 = (short*)(ws + W3_OFF);
    float* b1 = (float*)(ws + B1_OFF);
    float* b2 = (float*)(ws + B2_OFF);
    float* b3 = (float*)(ws + B3_OFF);
    float* st = (float*)(ws + ST_OFF);
    short* zp = (short*)(ws + ZP_OFF);

    hipMemsetAsync(al, 0, AL_SZ, stream);       // zero-pad columns 97..127 of al
    hipMemsetAsync(st, 0, 1024 + 256, stream);  // BN stat accumulators + zero page

    repack_all<<<(RT3+255)/256, 256, 0, stream>>>(Wc1, bc1, w1, b1,
                                                  Wc2, bc2, w2, b2,
                                                  Wc3, bc3, w3, b3);

    xproj_kernel<<<(T_STEPS*NN)/256, 256, 0, stream>>>(X, Wih, bih, bhh, xp);

    lstm_kernel<<<(NCHUNK*NN*2)/256, 256, 0, stream>>>(xp, Whh, al);

    conv_pipe<128,224,false><<<dim3(M_TOT/256, 2), 256, 0, stream>>>(al, w1, b1, f1, nullptr, zp);
    conv_pipe<224,224,false><<<dim3(M_TOT/256, 2), 256, 0, stream>>>(f1, w2, b2, f2, nullptr, zp);
    conv_pipe<224,112,true ><<<dim3(M_TOT/256, 1), 256, 0, stream>>>(f2, w3, b3, f3, st, zp);

    final_kernel<<<(T_STEPS*NN)/256, 256, 0, stream>>>(f3, st, gam, bet, Wl, bl, (float*)d_out);
}